// Round 11
// baseline (497.010 us; speedup 1.0000x reference)
//
#include <hip/hip_runtime.h>
#include <hip/hip_bf16.h>
#include <math.h>

// GPT decoder layer, MI355X/gfx950. bf16 MFMA GEMMs + fused flash attention.
// B=4 S=2048 D=1024 H=16 DH=64 F=4096.  Workspace layout (bytes):
//   [0,6M)      WqkvT  bf16 [3072][1024]   (pre-transposed, k-contiguous)
//   [6M,8M)     WoT    bf16 [1024][1024]
//   [8M,16M)    W1T    bf16 [4096][1024]
//   [16M,24M)   W2T    bf16 [1024][4096]
//   [24M,40M)   hbuf   bf16 [8192][1024]   (h -> attn_out -> h2, reused)
//   [40M,104M)  big    bf16                (QKV [8192][3072], later ff1 [8192][4096])

#define Bz 4
#define Sz 2048
#define Dz 1024
#define Hz 16
#define DHz 64
#define Fz 4096
#define Mz 8192

typedef float f32x4 __attribute__((ext_vector_type(4)));
typedef __bf16 bf16x8 __attribute__((ext_vector_type(8)));
typedef __bf16 bf16x4 __attribute__((ext_vector_type(4)));
typedef short s16x4 __attribute__((ext_vector_type(4)));

#define GLOAD_LDS16(g, l)                                                                   \
  __builtin_amdgcn_global_load_lds((const __attribute__((address_space(1))) unsigned int*)(g), \
                                   (__attribute__((address_space(3))) unsigned int*)(l), 16, 0, 0)

static __device__ __forceinline__ unsigned short f2bu(float f) {
  unsigned int u = __float_as_uint(f);
  u += 0x7fffu + ((u >> 16) & 1u);   // RNE to bf16
  return (unsigned short)(u >> 16);
}

static __device__ __forceinline__ f32x4 mfma32(bf16x8 a, bf16x8 b, f32x4 c) {
  return __builtin_amdgcn_mfma_f32_16x16x32_bf16(a, b, c, 0, 0, 0);
}
static __device__ __forceinline__ f32x4 mfma16(s16x4 a, s16x4 b, f32x4 c) {
#if __has_builtin(__builtin_amdgcn_mfma_f32_16x16x16bf16_1k)
  return __builtin_amdgcn_mfma_f32_16x16x16bf16_1k(a, b, c, 0, 0, 0);
#else
  asm("v_mfma_f32_16x16x16_bf16 %0, %1, %2, %0" : "+v"(c) : "v"(a), "v"(b));
  return c;
#endif
}

// hardware transpose read: lane l elem j <- lds[base + (l&15) + j*16 + (l>>4)*64] (bf16 elems)
template <int OFF>
static __device__ __forceinline__ s16x4 tr16(unsigned addr) {
  s16x4 r;
  asm volatile("ds_read_b64_tr_b16 %0, %1 offset:%2" : "=v"(r) : "v"(addr), "i"(OFF));
  return r;
}

// ---------------- weight packing ----------------

__global__ __launch_bounds__(256) void pack_qkv(
    const float* __restrict__ wq, const float* __restrict__ wk, const float* __restrict__ wv,
    unsigned short* __restrict__ outW)  // [3072][1024], row n = proj*1024 + h*64 + e, col = d
{
  __shared__ float tile[64][65];
  const int blk = blockIdx.x;       // 768 = 16 dchunk x 16 h x 3 proj
  const int dc = blk & 15;
  const int h  = (blk >> 4) & 15;
  const int p  = blk >> 8;
  const float* w = p == 0 ? wq : (p == 1 ? wk : wv);
  const int tid = threadIdx.x;
#pragma unroll
  for (int i = 0; i < 4; ++i) {
    int idx = i * 256 + tid;
    int dl = idx >> 4;
    int e0 = (idx & 15) * 4;
    const float4 v = *(const float4*)&w[(size_t)(h * 1024 + dc * 64 + dl) * 64 + e0];
    tile[dl][e0 + 0] = v.x; tile[dl][e0 + 1] = v.y;
    tile[dl][e0 + 2] = v.z; tile[dl][e0 + 3] = v.w;
  }
  __syncthreads();
#pragma unroll
  for (int i = 0; i < 4; ++i) {
    int idx = i * 256 + tid;
    int e = idx >> 4;
    int d0 = (idx & 15) * 4;
    ushort4 o;
    o.x = f2bu(tile[d0 + 0][e]); o.y = f2bu(tile[d0 + 1][e]);
    o.z = f2bu(tile[d0 + 2][e]); o.w = f2bu(tile[d0 + 3][e]);
    *(ushort4*)&outW[(size_t)(p * 1024 + h * 64 + e) * 1024 + dc * 64 + d0] = o;
  }
}

__global__ __launch_bounds__(256) void transpose_f32_to_bf16(
    const float* __restrict__ in, unsigned short* __restrict__ out, int R, int C)
{ // in [R][C] fp32 -> out [C][R] bf16
  __shared__ float tile[32][33];
  int c0 = blockIdx.x * 32, r0 = blockIdx.y * 32;
  int x = threadIdx.x, y = threadIdx.y;
#pragma unroll
  for (int i = 0; i < 32; i += 8)
    tile[y + i][x] = in[(size_t)(r0 + y + i) * C + c0 + x];
  __syncthreads();
#pragma unroll
  for (int i = 0; i < 32; i += 8)
    out[(size_t)(c0 + y + i) * R + r0 + x] = f2bu(tile[x][y + i]);
}

// ---------------- layernorm ----------------

__global__ __launch_bounds__(256) void ln_kernel(
    const float* __restrict__ x, const float* __restrict__ gamma, const float* __restrict__ beta,
    unsigned short* __restrict__ outH)
{
  const int row = blockIdx.x;
  const int tid = threadIdx.x;
  const float4 v = ((const float4*)(x + (size_t)row * Dz))[tid];
  float s = v.x + v.y + v.z + v.w;
  float s2 = v.x * v.x + v.y * v.y + v.z * v.z + v.w * v.w;
#pragma unroll
  for (int o = 32; o > 0; o >>= 1) {
    s += __shfl_xor(s, o);
    s2 += __shfl_xor(s2, o);
  }
  __shared__ float ss[4], ss2[4];
  if ((tid & 63) == 0) { ss[tid >> 6] = s; ss2[tid >> 6] = s2; }
  __syncthreads();
  s = ss[0] + ss[1] + ss[2] + ss[3];
  s2 = ss2[0] + ss2[1] + ss2[2] + ss2[3];
  const float mean = s * (1.0f / Dz);
  const float rstd = rsqrtf(s2 * (1.0f / Dz) - mean * mean + 1e-5f);
  const float4 g4 = ((const float4*)gamma)[tid];
  const float4 b4 = ((const float4*)beta)[tid];
  ushort4 o;
  o.x = f2bu((v.x - mean) * rstd * g4.x + b4.x);
  o.y = f2bu((v.y - mean) * rstd * g4.y + b4.y);
  o.z = f2bu((v.z - mean) * rstd * g4.z + b4.z);
  o.w = f2bu((v.w - mean) * rstd * g4.w + b4.w);
  ((ushort4*)(outH + (size_t)row * Dz))[tid] = o;
}

// ---------------- GEMM BMx256, BK=32, DEPTH=4, 8 waves, UNPINNED ----------------
// C[M,N] = A[M,K](bf16) @ BT[N,K]^T(bf16).  BN=256.
// R10 post-mortem: super-chunk ordering + FFN1 BM=128 regressed (shape traffic
// dominated) -> reverted both; base = R9 (441us, best).
// One variable vs R9: BK=32 / DEPTH=4 quad-buffer = TRUE 3-tile prefetch lead
// (~900+cyc = HBM-miss latency). R8's version of this was confounded by (a)
// order-pinning (removed in R9, -50us alone) and (b) a swizzle bug: with 64B
// rows, XOR by (row&3) spans only 64B -> 4-way bank conflicts (6.3M). Fix:
// XOR chunk slot by ((row>>1)&3): addr%128 = 64*(row&1) + 16*(kgrp^((row>>1)&3))
// -> 8 distinct 16B slots per 16-lane group, same 2-way-max structure as the
// proven BK=64 swizzle (measured 0 conflicts).
// Per tile: issue(t+3) -> counted vmcnt(3CH/2CH/CH/0; never 0 mid-loop) ->
// s_barrier -> UNPINNED compute (compiler co-schedules ds_read+MFMA; m141/R9)
// -> sched_barrier+s_barrier. Slot hazard: issue at t targets (t+3)&3 =
// (t-1)&3, last read in tile t-1, sealed by its trailing barrier.

enum { EPI_BF16 = 0, EPI_GELU_BF16 = 1, EPI_RES_F32 = 2, EPI_BIAS_RES_F32 = 3 };

template <int BM, int EPI>
__global__ __launch_bounds__(512, 2) void gemm256(
    const unsigned short* __restrict__ A,   // [M,K] bf16
    const unsigned short* __restrict__ BT,  // [N,K] bf16
    int M, int N, int K,
    const float* bias, const float* resid,  // resid/outf may alias: no __restrict__
    unsigned short* outb, float* outf)
{
  constexpr int BN = 256, BK = 32, DEPTH = 4;
  constexpr int ACH = BM / 128;        // A stage chunks/tile: 1 or 2
  constexpr int BCH = 2;               // B stage chunks/tile
  constexpr int CH = ACH + BCH;        // 3 or 4
  constexpr int MREP = BM / 32;        // 4 or 8
  __shared__ unsigned short As[DEPTH][BM * BK];
  __shared__ unsigned short Bs[DEPTH][BN * BK];

  const int tid = threadIdx.x;
  const int lane = tid & 63;
  const int wid = tid >> 6;
  const int wr = wid >> 2;        // 2 wave-rows of BM/2
  const int wc = wid & 3;         // 4 wave-cols of 64
  const int rsel = lane & 15;
  const int kgrp = lane >> 4;

  // XCD-chunked bijective swizzle (nwg % 8 == 0 for all our grids) -- R9 mapping
  const int nwg = gridDim.x;
  const int bid = blockIdx.x;
  const int id2 = (bid & 7) * (nwg >> 3) + (bid >> 3);
  const int nbx = N / BN;
  const int n0 = (id2 % nbx) * BN;
  const int m0 = (id2 / nbx) * BM;

  f32x4 acc[MREP][4] = {};

  auto issue = [&](int kt, int slot) {
#pragma unroll
    for (int r = 0; r < ACH; ++r) {
      int gc = r * 512 + tid;
      int row = gc >> 2;                       // 4 chunks of 16B per 32-elem row
      int kcs = (gc & 3) ^ ((row >> 1) & 3);   // corrected swizzle (128B span)
      GLOAD_LDS16(A + (size_t)(m0 + row) * K + kt * BK + kcs * 8, &As[slot][gc * 8]);
    }
#pragma unroll
    for (int r = 0; r < BCH; ++r) {
      int gc = r * 512 + tid;
      int row = gc >> 2;
      int kcs = (gc & 3) ^ ((row >> 1) & 3);
      GLOAD_LDS16(BT + (size_t)(n0 + row) * K + kt * BK + kcs * 8, &Bs[slot][gc * 8]);
    }
  };

  const int T = K >> 5;
  issue(0, 0); issue(1, 1); issue(2, 2);

  for (int t = 0; t < T; ++t) {
    const int slot = t & 3;
    if (t + 3 < T) issue(t + 3, (t + 3) & 3);
    int rem = T - 1 - t; if (rem > 3) rem = 3;
    if constexpr (CH == 4) {
      if (rem == 3)      asm volatile("s_waitcnt vmcnt(12)" ::: "memory");
      else if (rem == 2) asm volatile("s_waitcnt vmcnt(8)" ::: "memory");
      else if (rem == 1) asm volatile("s_waitcnt vmcnt(4)" ::: "memory");
      else               asm volatile("s_waitcnt vmcnt(0)" ::: "memory");
    } else {
      if (rem == 3)      asm volatile("s_waitcnt vmcnt(9)" ::: "memory");
      else if (rem == 2) asm volatile("s_waitcnt vmcnt(6)" ::: "memory");
      else if (rem == 1) asm volatile("s_waitcnt vmcnt(3)" ::: "memory");
      else               asm volatile("s_waitcnt vmcnt(0)" ::: "memory");
    }
    __builtin_amdgcn_sched_barrier(0);
    __builtin_amdgcn_s_barrier();       // tile t staged for all waves
    __builtin_amdgcn_sched_barrier(0);  // no frag read hoists above the barrier

    const unsigned short* Ab = As[slot];
    const unsigned short* Bb = Bs[slot];
    __builtin_amdgcn_s_setprio(1);
    {
      bf16x8 bfr[4], af[MREP];
#pragma unroll
      for (int nf = 0; nf < 4; ++nf) {
        int br = wc * 64 + nf * 16 + rsel;
        bfr[nf] = *(const bf16x8*)&Bb[br * BK + ((kgrp ^ ((br >> 1) & 3)) * 8)];
      }
#pragma unroll
      for (int mf = 0; mf < MREP; ++mf) {
        int ar = wr * (BM / 2) + mf * 16 + rsel;
        af[mf] = *(const bf16x8*)&Ab[ar * BK + ((kgrp ^ ((ar >> 1) & 3)) * 8)];
      }
      // no lgkmcnt/sched_barrier here: compiler co-schedules reads with MFMAs.
#pragma unroll
      for (int mf = 0; mf < MREP; ++mf)
#pragma unroll
        for (int nf = 0; nf < 4; ++nf)
          acc[mf][nf] = mfma32(af[mf], bfr[nf], acc[mf][nf]);
    }
    __builtin_amdgcn_s_setprio(0);
    __builtin_amdgcn_sched_barrier(0);  // no frag read sinks below the barrier
    __builtin_amdgcn_s_barrier();       // slot free before (t+4)'s issue
  }

#pragma unroll
  for (int mf = 0; mf < MREP; ++mf) {
#pragma unroll
    for (int nf = 0; nf < 4; ++nf) {
      const int n = n0 + wc * 64 + nf * 16 + rsel;
#pragma unroll
      for (int j = 0; j < 4; ++j) {
        const int m = m0 + wr * (BM / 2) + mf * 16 + kgrp * 4 + j;
        const size_t idx = (size_t)m * N + n;
        float v = acc[mf][nf][j];
        if constexpr (EPI == EPI_BF16) {
          outb[idx] = f2bu(v);
        } else if constexpr (EPI == EPI_GELU_BF16) {
          v += bias[n];
          v = 0.5f * v * (1.0f + erff(v * 0.70710678118654752f));
          outb[idx] = f2bu(v);
        } else if constexpr (EPI == EPI_RES_F32) {
          outf[idx] = v + resid[idx];
        } else {
          outf[idx] = v + bias[n] + resid[idx];
        }
      }
    }
  }
}

// ---------------- fused causal flash attention (unchanged, R9) ----------------
// Block = PAIR of q-tiles {i, 31-i} x head x batch, grid 1024 = 4 blocks/CU.
// S^T = K @ Q^T via mfma 16x16x32; P^T stays in registers as the B-frag of
// mfma 16x16x16 for O^T = V^T @ P^T; V read with ds_read_b64_tr_b16, V-frags
// shared by both q-sets. Softmax in log2 domain with defer-rescale (THR=8).

__global__ __launch_bounds__(256, 4) void attn_kernel(
    const unsigned short* __restrict__ QKV,  // [Mz][3072] bf16 (q|k|v, feature h*64+e)
    unsigned short* __restrict__ outA)       // [Mz][Dz]  bf16
{
  __shared__ unsigned short Kt[64 * 64];  // [key][d], 16B d-chunk XOR-swizzled by key&7
  __shared__ unsigned short Vs[64 * 64];  // subtiled for tr16 reads
  const int pi = blockIdx.x;  // 0..15
  const int hh = blockIdx.y;
  const int bb = blockIdx.z;
  const int tid = threadIdx.x;
  const int lane = tid & 63;
  const int w = tid >> 6;
  const int rsel = lane & 15;
  const int kgrp = lane >> 4;
  const int qt[2] = {pi, 31 - pi};

  bf16x8 qf0[2], qf1[2];
  int qg[2];
#pragma unroll
  for (int s = 0; s < 2; ++s) {
    qg[s] = qt[s] * 64 + w * 16 + rsel;
    const size_t rowQ = (size_t)(bb * Sz + qg[s]) * 3072 + hh * 64;
    qf0[s] = *(const bf16x8*)&QKV[rowQ + kgrp * 8];
    qf1[s] = *(const bf16x8*)&QKV[rowQ + 32 + kgrp * 8];
  }

  f32x4 accO[2][4] = {};  // [set][df]; O^T row=d=(df*16+kgrp*4+j), col=q=rsel
  float mr[2] = {-INFINITY, -INFINITY};
  float lr[2] = {0.0f, 0.0f};

  auto vs3 = (__attribute__((address_space(3))) unsigned short*)Vs;
  const unsigned vbase = (unsigned)(uintptr_t)vs3 + (unsigned)lane * 8u;
  constexpr float SCL = 0.18033688011112042f;  // log2(e)/sqrt(64)

  // S^T + online softmax (log2 domain, defer-rescale) -> P^T bf16 B-frags
  auto proc = [&](const bf16x8& q0, const bf16x8& q1, float& mrun, float& lrun,
                  f32x4* accS, s16x4* pb, bool edge, int qgs, int kb) {
    f32x4 sc[4];
    __builtin_amdgcn_s_setprio(1);
#pragma unroll
    for (int kf = 0; kf < 4; ++kf) {
      int key = kf * 16 + rsel;
      bf16x8 k0 = *(const bf16x8*)&Kt[key * 64 + ((kgrp ^ (key & 7)) * 8)];
      bf16x8 k1 = *(const bf16x8*)&Kt[key * 64 + (((4 + kgrp) ^ (key & 7)) * 8)];
      f32x4 s = {};
      s = mfma32(k0, q0, s);
      s = mfma32(k1, q1, s);
      sc[kf] = s;
    }
    __builtin_amdgcn_s_setprio(0);
    float tmax = -INFINITY;
#pragma unroll
    for (int kf = 0; kf < 4; ++kf)
#pragma unroll
      for (int j = 0; j < 4; ++j) {
        float v = sc[kf][j] * SCL;
        if (edge) {
          int keyg = kb + kf * 16 + kgrp * 4 + j;
          if (keyg > qgs) v = -INFINITY;
        }
        sc[kf][j] = v;
        tmax = fmaxf(tmax, v);
      }
    tmax = fmaxf(tmax, __shfl_xor(tmax, 16));
    tmax = fmaxf(tmax, __shfl_xor(tmax, 32));
    // defer-rescale (T13): skip O/l rescale while max growth stays under 8 (log2 units)
    if (!__all(tmax <= mrun + 8.0f)) {
      const float mnew = fmaxf(mrun, tmax);
      const float corr = exp2f(mrun - mnew);
      lrun *= corr;
#pragma unroll
      for (int df = 0; df < 4; ++df) accS[df] *= corr;
      mrun = mnew;
    }
    float psum = 0.0f;
#pragma unroll
    for (int kf = 0; kf < 4; ++kf) {
      bf16x4 pv;
#pragma unroll
      for (int j = 0; j < 4; ++j) {
        float e = exp2f(sc[kf][j] - mrun);
        psum += e;
        pv[j] = (__bf16)e;  // v_cvt_pk_bf16_f32 pairs
      }
      pb[kf] = __builtin_bit_cast(s16x4, pv);
    }
    psum += __shfl_xor(psum, 16);
    psum += __shfl_xor(psum, 32);
    lrun += psum;
  };

  for (int kt = 0; kt <= qt[1]; ++kt) {
    const int kb = kt * 64;
    if (kt) __syncthreads();  // prev tile's LDS reads done before overwrite
    // stage K: LDS linear, global d-chunk XOR-swizzled by key&7
#pragma unroll
    for (int r = 0; r < 2; ++r) {
      int c = r * 256 + tid;
      int key = c >> 3;
      int dcs = (c & 7) ^ (key & 7);
      GLOAD_LDS16(QKV + (size_t)(bb * Sz + kb + key) * 3072 + 1024 + hh * 64 + dcs * 8,
                  &Kt[c * 8]);
    }
    // stage V: LDS linear; source permuted so LDS holds subtiled layout
#pragma unroll
    for (int r = 0; r < 2; ++r) {
      int c = r * 256 + tid;
      int key = ((c >> 3) & 15) * 4 + ((c >> 1) & 3);
      int d = (c >> 7) * 16 + (c & 1) * 8;
      GLOAD_LDS16(QKV + (size_t)(bb * Sz + kb + key) * 3072 + 2048 + hh * 64 + d,
                  &Vs[c * 8]);
    }
    __syncthreads();

    s16x4 pb[2][4];
#pragma unroll
    for (int s = 0; s < 2; ++s)
      if (kt <= qt[s])
        proc(qf0[s], qf1[s], mr[s], lr[s], accO[s], pb[s], kt == qt[s], qg[s], kb);

    // O^T += V^T @ P^T — V-frags shared by both q-sets
#pragma unroll
    for (int df = 0; df < 4; ++df) {
      unsigned a = vbase + df * 2048;
      s16x4 vf0 = tr16<0>(a);
      s16x4 vf1 = tr16<512>(a);
      s16x4 vf2 = tr16<1024>(a);
      s16x4 vf3 = tr16<1536>(a);
      asm volatile("s_waitcnt lgkmcnt(0)" ::: "memory");
      __builtin_amdgcn_sched_barrier(0);
      __builtin_amdgcn_s_setprio(1);
#pragma unroll
      for (int s = 0; s < 2; ++s) {
        if (kt <= qt[s]) {
          accO[s][df] = mfma16(vf0, pb[s][0], accO[s][df]);
          accO[s][df] = mfma16(vf1, pb[s][1], accO[s][df]);
          accO[s][df] = mfma16(vf2, pb[s][2], accO[s][df]);
          accO[s][df] = mfma16(vf3, pb[s][3], accO[s][df]);
        }
      }
      __builtin_amdgcn_s_setprio(0);
    }
  }

#pragma unroll
  for (int s = 0; s < 2; ++s) {
    const float rl = 1.0f / lr[s];
    const size_t orow = (size_t)(bb * Sz + qg[s]) * Dz + hh * 64;
#pragma unroll
    for (int df = 0; df < 4; ++df) {
      s16x4 o;
#pragma unroll
      for (int j = 0; j < 4; ++j) o[j] = (short)f2bu(accO[s][df][j] * rl);
      *(s16x4*)&outA[orow + df * 16 + kgrp * 4] = o;
    }
  }
}

// ---------------- launch ----------------

extern "C" void kernel_launch(void* const* d_in, const int* in_sizes, int n_in,
                              void* d_out, int out_size, void* d_ws, size_t ws_size,
                              hipStream_t stream) {
  const float* x   = (const float*)d_in[0];
  // d_in[1] = mask (causal, known) — unused
  const float* wq  = (const float*)d_in[2];
  const float* wk  = (const float*)d_in[3];
  const float* wv  = (const float*)d_in[4];
  const float* wo  = (const float*)d_in[5];
  const float* w1  = (const float*)d_in[6];
  const float* b1  = (const float*)d_in[7];
  const float* w2  = (const float*)d_in[8];
  const float* b2  = (const float*)d_in[9];
  const float* g1  = (const float*)d_in[10];
  const float* be1 = (const float*)d_in[11];
  const float* g2  = (const float*)d_in[12];
  const float* be2 = (const float*)d_in[13];
  float* out = (float*)d_out;

  char* ws = (char*)d_ws;
  unsigned short* WqkvT = (unsigned short*)(ws);
  unsigned short* WoT   = (unsigned short*)(ws + 6291456);
  unsigned short* W1T   = (unsigned short*)(ws + 8388608);
  unsigned short* W2T   = (unsigned short*)(ws + 16777216);
  unsigned short* hbuf  = (unsigned short*)(ws + 25165824);
  unsigned short* big   = (unsigned short*)(ws + 41943040);  // QKV, later ff1

  dim3 tb(32, 8);
  pack_qkv<<<768, 256, 0, stream>>>(wq, wk, wv, WqkvT);
  transpose_f32_to_bf16<<<dim3(32, 32), tb, 0, stream>>>(wo, WoT, 1024, 1024);
  transpose_f32_to_bf16<<<dim3(128, 32), tb, 0, stream>>>(w1, W1T, 1024, 4096);
  transpose_f32_to_bf16<<<dim3(32, 128), tb, 0, stream>>>(w2, W2T, 4096, 1024);

  ln_kernel<<<Mz, 256, 0, stream>>>(x, g1, be1, hbuf);
  gemm256<128, EPI_BF16><<<768, 512, 0, stream>>>(
      hbuf, WqkvT, Mz, 3072, 1024, nullptr, nullptr, big, nullptr);
  attn_kernel<<<dim3(16, 16, 4), 256, 0, stream>>>(big, hbuf);
  gemm256<128, EPI_RES_F32><<<256, 512, 0, stream>>>(
      hbuf, WoT, Mz, 1024, 1024, nullptr, x, nullptr, out);
  ln_kernel<<<Mz, 256, 0, stream>>>(out, g2, be2, hbuf);
  gemm256<256, EPI_GELU_BF16><<<512, 512, 0, stream>>>(
      hbuf, W1T, Mz, Fz, 1024, b1, nullptr, big, nullptr);
  gemm256<128, EPI_BIAS_RES_F32><<<256, 512, 0, stream>>>(
      big, W2T, Mz, 1024, Fz, b2, out, nullptr, out);
}

// Round 12
// 453.760 us; speedup vs baseline: 1.0953x; 1.0953x over previous
//
#include <hip/hip_runtime.h>
#include <hip/hip_bf16.h>
#include <math.h>

// GPT decoder layer, MI355X/gfx950. bf16 MFMA GEMMs + fused flash attention.
// B=4 S=2048 D=1024 H=16 DH=64 F=4096.  Workspace layout (bytes):
//   [0,6M)      WqkvT  bf16 [3072][1024]   (pre-transposed, k-contiguous)
//   [6M,8M)     WoT    bf16 [1024][1024]
//   [8M,16M)    W1T    bf16 [4096][1024]
//   [16M,24M)   W2T    bf16 [1024][4096]
//   [24M,40M)   hbuf   bf16 [8192][1024]   (h -> attn_out -> h2, reused)
//   [40M,104M)  big    bf16                (QKV [8192][3072], later ff1 [8192][4096])

#define Bz 4
#define Sz 2048
#define Dz 1024
#define Hz 16
#define DHz 64
#define Fz 4096
#define Mz 8192

typedef float f32x4 __attribute__((ext_vector_type(4)));
typedef __bf16 bf16x8 __attribute__((ext_vector_type(8)));
typedef __bf16 bf16x4 __attribute__((ext_vector_type(4)));
typedef short s16x4 __attribute__((ext_vector_type(4)));

#define GLOAD_LDS16(g, l)                                                                   \
  __builtin_amdgcn_global_load_lds((const __attribute__((address_space(1))) unsigned int*)(g), \
                                   (__attribute__((address_space(3))) unsigned int*)(l), 16, 0, 0)

static __device__ __forceinline__ unsigned short f2bu(float f) {
  unsigned int u = __float_as_uint(f);
  u += 0x7fffu + ((u >> 16) & 1u);   // RNE to bf16
  return (unsigned short)(u >> 16);
}

static __device__ __forceinline__ f32x4 mfma32(bf16x8 a, bf16x8 b, f32x4 c) {
  return __builtin_amdgcn_mfma_f32_16x16x32_bf16(a, b, c, 0, 0, 0);
}
static __device__ __forceinline__ f32x4 mfma16(s16x4 a, s16x4 b, f32x4 c) {
#if __has_builtin(__builtin_amdgcn_mfma_f32_16x16x16bf16_1k)
  return __builtin_amdgcn_mfma_f32_16x16x16bf16_1k(a, b, c, 0, 0, 0);
#else
  asm("v_mfma_f32_16x16x16_bf16 %0, %1, %2, %0" : "+v"(c) : "v"(a), "v"(b));
  return c;
#endif
}

// hardware transpose read: lane l elem j <- lds[base + (l&15) + j*16 + (l>>4)*64] (bf16 elems)
template <int OFF>
static __device__ __forceinline__ s16x4 tr16(unsigned addr) {
  s16x4 r;
  asm volatile("ds_read_b64_tr_b16 %0, %1 offset:%2" : "=v"(r) : "v"(addr), "i"(OFF));
  return r;
}

// ---------------- weight packing ----------------

__global__ __launch_bounds__(256) void pack_qkv(
    const float* __restrict__ wq, const float* __restrict__ wk, const float* __restrict__ wv,
    unsigned short* __restrict__ outW)  // [3072][1024], row n = proj*1024 + h*64 + e, col = d
{
  __shared__ float tile[64][65];
  const int blk = blockIdx.x;       // 768 = 16 dchunk x 16 h x 3 proj
  const int dc = blk & 15;
  const int h  = (blk >> 4) & 15;
  const int p  = blk >> 8;
  const float* w = p == 0 ? wq : (p == 1 ? wk : wv);
  const int tid = threadIdx.x;
#pragma unroll
  for (int i = 0; i < 4; ++i) {
    int idx = i * 256 + tid;
    int dl = idx >> 4;
    int e0 = (idx & 15) * 4;
    const float4 v = *(const float4*)&w[(size_t)(h * 1024 + dc * 64 + dl) * 64 + e0];
    tile[dl][e0 + 0] = v.x; tile[dl][e0 + 1] = v.y;
    tile[dl][e0 + 2] = v.z; tile[dl][e0 + 3] = v.w;
  }
  __syncthreads();
#pragma unroll
  for (int i = 0; i < 4; ++i) {
    int idx = i * 256 + tid;
    int e = idx >> 4;
    int d0 = (idx & 15) * 4;
    ushort4 o;
    o.x = f2bu(tile[d0 + 0][e]); o.y = f2bu(tile[d0 + 1][e]);
    o.z = f2bu(tile[d0 + 2][e]); o.w = f2bu(tile[d0 + 3][e]);
    *(ushort4*)&outW[(size_t)(p * 1024 + h * 64 + e) * 1024 + dc * 64 + d0] = o;
  }
}

__global__ __launch_bounds__(256) void transpose_f32_to_bf16(
    const float* __restrict__ in, unsigned short* __restrict__ out, int R, int C)
{ // in [R][C] fp32 -> out [C][R] bf16
  __shared__ float tile[32][33];
  int c0 = blockIdx.x * 32, r0 = blockIdx.y * 32;
  int x = threadIdx.x, y = threadIdx.y;
#pragma unroll
  for (int i = 0; i < 32; i += 8)
    tile[y + i][x] = in[(size_t)(r0 + y + i) * C + c0 + x];
  __syncthreads();
#pragma unroll
  for (int i = 0; i < 32; i += 8)
    out[(size_t)(c0 + y + i) * R + r0 + x] = f2bu(tile[x][y + i]);
}

// ---------------- layernorm ----------------

__global__ __launch_bounds__(256) void ln_kernel(
    const float* __restrict__ x, const float* __restrict__ gamma, const float* __restrict__ beta,
    unsigned short* __restrict__ outH)
{
  const int row = blockIdx.x;
  const int tid = threadIdx.x;
  const float4 v = ((const float4*)(x + (size_t)row * Dz))[tid];
  float s = v.x + v.y + v.z + v.w;
  float s2 = v.x * v.x + v.y * v.y + v.z * v.z + v.w * v.w;
#pragma unroll
  for (int o = 32; o > 0; o >>= 1) {
    s += __shfl_xor(s, o);
    s2 += __shfl_xor(s2, o);
  }
  __shared__ float ss[4], ss2[4];
  if ((tid & 63) == 0) { ss[tid >> 6] = s; ss2[tid >> 6] = s2; }
  __syncthreads();
  s = ss[0] + ss[1] + ss[2] + ss[3];
  s2 = ss2[0] + ss2[1] + ss2[2] + ss2[3];
  const float mean = s * (1.0f / Dz);
  const float rstd = rsqrtf(s2 * (1.0f / Dz) - mean * mean + 1e-5f);
  const float4 g4 = ((const float4*)gamma)[tid];
  const float4 b4 = ((const float4*)beta)[tid];
  ushort4 o;
  o.x = f2bu((v.x - mean) * rstd * g4.x + b4.x);
  o.y = f2bu((v.y - mean) * rstd * g4.y + b4.y);
  o.z = f2bu((v.z - mean) * rstd * g4.z + b4.z);
  o.w = f2bu((v.w - mean) * rstd * g4.w + b4.w);
  ((ushort4*)(outH + (size_t)row * Dz))[tid] = o;
}

// ---------------- GEMM BMx256, BK=64, 8 waves (2Mx4N), UNPINNED (R9-exact) ----------
// C[M,N] = A[M,K](bf16) @ BT[N,K]^T(bf16).  BN=256 -> 32 MFMA per kk-half.
// R9 = best measured (441us). R10 (super-chunk, BM128-FFN1) and R11 (BK=32/DEPTH=4)
// both regressed -> reverted. Intra-tile pinning removed (m141: order-pinning
// defeats compiler's fine-grained lgkmcnt co-scheduling). Fences only at tile
// boundaries: counted vmcnt + s_barrier, sched_barrier+s_barrier at tile end.
// BM=128: DEPTH=3 triple buffer; BM=256: DEPTH=2. Issue tile t+DEPTH-1 at tile t.
// LDS 16B chunks XOR-swizzled by row&7 (pre-swizzled global source, linear dest).

enum { EPI_BF16 = 0, EPI_GELU_BF16 = 1, EPI_RES_F32 = 2, EPI_BIAS_RES_F32 = 3 };

template <int BM, int EPI>
__global__ __launch_bounds__(512, 2) void gemm256(
    const unsigned short* __restrict__ A,   // [M,K] bf16
    const unsigned short* __restrict__ BT,  // [N,K] bf16
    int M, int N, int K,
    const float* bias, const float* resid,  // resid/outf may alias: no __restrict__
    unsigned short* outb, float* outf)
{
  constexpr int BN = 256, BK = 64;
  constexpr int DEPTH = (BM == 128) ? 3 : 2;
  constexpr int ACH = (BM * BK * 2) / (512 * 16);  // A stage chunks: 2 or 4
  constexpr int BCH = (BN * BK * 2) / (512 * 16);  // 4
  constexpr int MREP = BM / 32;                    // wave m-frags: 4 or 8
  __shared__ unsigned short As[DEPTH][BM * BK];
  __shared__ unsigned short Bs[DEPTH][BN * BK];

  const int tid = threadIdx.x;
  const int lane = tid & 63;
  const int wid = tid >> 6;
  const int wr = wid >> 2;        // 2 wave-rows of BM/2
  const int wc = wid & 3;         // 4 wave-cols of 64
  const int rsel = lane & 15;
  const int kgrp = lane >> 4;

  // XCD-chunked bijective swizzle (nwg % 8 == 0 for all our grids)
  const int nwg = gridDim.x;
  const int bid = blockIdx.x;
  const int id2 = (bid & 7) * (nwg >> 3) + (bid >> 3);
  const int nbx = N / BN;
  const int n0 = (id2 % nbx) * BN;
  const int m0 = (id2 / nbx) * BM;

  f32x4 acc[MREP][4] = {};

  auto issue = [&](int kt, int b) {
#pragma unroll
    for (int r = 0; r < ACH; ++r) {
      int gc = r * 512 + tid;
      int row = gc >> 3;
      int kcs = (gc & 7) ^ (row & 7);
      GLOAD_LDS16(A + (size_t)(m0 + row) * K + kt * BK + kcs * 8, &As[b][gc * 8]);
    }
#pragma unroll
    for (int r = 0; r < BCH; ++r) {
      int gc = r * 512 + tid;
      int row = gc >> 3;
      int kcs = (gc & 7) ^ (row & 7);
      GLOAD_LDS16(BT + (size_t)(n0 + row) * K + kt * BK + kcs * 8, &Bs[b][gc * 8]);
    }
  };

  const int T = K >> 6;
#pragma unroll
  for (int d = 0; d < DEPTH - 1; ++d) issue(d, d);

  for (int t = 0; t < T; ++t) {
    const int b = t % DEPTH;
    if (t + DEPTH - 1 < T) issue(t + DEPTH - 1, (t + DEPTH - 1) % DEPTH);
    int rem = T - 1 - t;
    if (rem > DEPTH - 1) rem = DEPTH - 1;
    if constexpr (DEPTH == 3) {
      if (rem == 2)      asm volatile("s_waitcnt vmcnt(12)" ::: "memory");
      else if (rem == 1) asm volatile("s_waitcnt vmcnt(6)" ::: "memory");
      else               asm volatile("s_waitcnt vmcnt(0)" ::: "memory");
    } else {
      if (rem == 1) asm volatile("s_waitcnt vmcnt(8)" ::: "memory");
      else          asm volatile("s_waitcnt vmcnt(0)" ::: "memory");
    }
    __builtin_amdgcn_sched_barrier(0);
    __builtin_amdgcn_s_barrier();   // tile t staged for all waves
    __builtin_amdgcn_sched_barrier(0);  // no frag read hoists above the barrier

    const unsigned short* Ab = As[b];
    const unsigned short* Bb = Bs[b];
    __builtin_amdgcn_s_setprio(1);
#pragma unroll
    for (int kk = 0; kk < 2; ++kk) {
      bf16x8 bfr[4], af[MREP];
#pragma unroll
      for (int nf = 0; nf < 4; ++nf) {
        int br = wc * 64 + nf * 16 + rsel;
        bfr[nf] = *(const bf16x8*)&Bb[br * BK + (((kk * 4 + kgrp) ^ (br & 7)) * 8)];
      }
#pragma unroll
      for (int mf = 0; mf < MREP; ++mf) {
        int ar = wr * (BM / 2) + mf * 16 + rsel;
        af[mf] = *(const bf16x8*)&Ab[ar * BK + (((kk * 4 + kgrp) ^ (ar & 7)) * 8)];
      }
      // no lgkmcnt/sched_barrier here: compiler emits fine-grained waits and
      // co-schedules these reads with the MFMAs below (m97/m141 lesson).
#pragma unroll
      for (int mf = 0; mf < MREP; ++mf)
#pragma unroll
        for (int nf = 0; nf < 4; ++nf)
          acc[mf][nf] = mfma32(af[mf], bfr[nf], acc[mf][nf]);
    }
    __builtin_amdgcn_s_setprio(0);
    __builtin_amdgcn_sched_barrier(0);  // no frag read sinks below the barrier
    __builtin_amdgcn_s_barrier();   // all waves done reading buf[b] before reuse
  }

#pragma unroll
  for (int mf = 0; mf < MREP; ++mf) {
#pragma unroll
    for (int nf = 0; nf < 4; ++nf) {
      const int n = n0 + wc * 64 + nf * 16 + rsel;
#pragma unroll
      for (int j = 0; j < 4; ++j) {
        const int m = m0 + wr * (BM / 2) + mf * 16 + kgrp * 4 + j;
        const size_t idx = (size_t)m * N + n;
        float v = acc[mf][nf][j];
        if constexpr (EPI == EPI_BF16) {
          outb[idx] = f2bu(v);
        } else if constexpr (EPI == EPI_GELU_BF16) {
          v += bias[n];
          v = 0.5f * v * (1.0f + erff(v * 0.70710678118654752f));
          outb[idx] = f2bu(v);
        } else if constexpr (EPI == EPI_RES_F32) {
          outf[idx] = v + resid[idx];
        } else {
          outf[idx] = v + bias[n] + resid[idx];
        }
      }
    }
  }
}

// ---------------- fused causal flash attention: counted-vmcnt K/V double-buffer ----
// Block = PAIR of q-tiles {i, 31-i} x head x batch, grid 1024.
// NEW vs R9: per-tile __syncthreads (which drains vmcnt(0) -> serial HBM/L2
// latency exposure each of ~33 tiles) replaced by the R9-proven GEMM pattern:
// stage(kt+1) into buf^1 at iter top -> s_waitcnt vmcnt(4) (stage = 4 gloads;
// FIFO drains Q-loads and stage(kt) first, leaves only stage(kt+1) in flight)
// -> raw s_barrier -> compute buf[cur] -> s_barrier (seals buf^1 for kt+2's
// stage; all LDS reads complete before trailing barrier: compiler lgkm waits
// for K-frags, explicit lgkmcnt(0) for tr16).
// S^T = K @ Q^T via mfma 16x16x32; P^T stays in registers as the B-frag of
// mfma 16x16x16 for O^T = V^T @ P^T; V read with ds_read_b64_tr_b16, V-frags
// shared by both q-sets. Softmax in log2 domain with defer-rescale (THR=8).

__global__ __launch_bounds__(256, 4) void attn_kernel(
    const unsigned short* __restrict__ QKV,  // [Mz][3072] bf16 (q|k|v, feature h*64+e)
    unsigned short* __restrict__ outA)       // [Mz][Dz]  bf16
{
  __shared__ unsigned short Kt[2][64 * 64];  // [key][d], 16B d-chunk XOR-swz by key&7
  __shared__ unsigned short Vs[2][64 * 64];  // subtiled for tr16 reads
  const int pi = blockIdx.x;  // 0..15
  const int hh = blockIdx.y;
  const int bb = blockIdx.z;
  const int tid = threadIdx.x;
  const int lane = tid & 63;
  const int w = tid >> 6;
  const int rsel = lane & 15;
  const int kgrp = lane >> 4;
  const int qt[2] = {pi, 31 - pi};

  bf16x8 qf0[2], qf1[2];
  int qg[2];
#pragma unroll
  for (int s = 0; s < 2; ++s) {
    qg[s] = qt[s] * 64 + w * 16 + rsel;
    const size_t rowQ = (size_t)(bb * Sz + qg[s]) * 3072 + hh * 64;
    qf0[s] = *(const bf16x8*)&QKV[rowQ + kgrp * 8];
    qf1[s] = *(const bf16x8*)&QKV[rowQ + 32 + kgrp * 8];
  }

  f32x4 accO[2][4] = {};  // [set][df]; O^T row=d=(df*16+kgrp*4+j), col=q=rsel
  float mr[2] = {-INFINITY, -INFINITY};
  float lr[2] = {0.0f, 0.0f};

  auto vs3 = (__attribute__((address_space(3))) unsigned short*)&Vs[0][0];
  const unsigned vbase = (unsigned)(uintptr_t)vs3 + (unsigned)lane * 8u;
  constexpr float SCL = 0.18033688011112042f;  // log2(e)/sqrt(64)

  auto stage = [&](int kt, int b) {  // 4 gloads/thread: 2 K chunks + 2 V chunks
    const int kb = kt * 64;
#pragma unroll
    for (int r = 0; r < 2; ++r) {
      int c = r * 256 + tid;
      int key = c >> 3;
      int dcs = (c & 7) ^ (key & 7);
      GLOAD_LDS16(QKV + (size_t)(bb * Sz + kb + key) * 3072 + 1024 + hh * 64 + dcs * 8,
                  &Kt[b][c * 8]);
    }
#pragma unroll
    for (int r = 0; r < 2; ++r) {
      int c = r * 256 + tid;
      int key = ((c >> 3) & 15) * 4 + ((c >> 1) & 3);
      int d = (c >> 7) * 16 + (c & 1) * 8;
      GLOAD_LDS16(QKV + (size_t)(bb * Sz + kb + key) * 3072 + 2048 + hh * 64 + d,
                  &Vs[b][c * 8]);
    }
  };

  // S^T + online softmax (log2 domain, defer-rescale) -> P^T bf16 B-frags
  auto proc = [&](const unsigned short* Kb, const bf16x8& q0, const bf16x8& q1,
                  float& mrun, float& lrun, f32x4* accS, s16x4* pb,
                  bool edge, int qgs, int kb) {
    f32x4 sc[4];
    __builtin_amdgcn_s_setprio(1);
#pragma unroll
    for (int kf = 0; kf < 4; ++kf) {
      int key = kf * 16 + rsel;
      bf16x8 k0 = *(const bf16x8*)&Kb[key * 64 + ((kgrp ^ (key & 7)) * 8)];
      bf16x8 k1 = *(const bf16x8*)&Kb[key * 64 + (((4 + kgrp) ^ (key & 7)) * 8)];
      f32x4 s = {};
      s = mfma32(k0, q0, s);
      s = mfma32(k1, q1, s);
      sc[kf] = s;
    }
    __builtin_amdgcn_s_setprio(0);
    float tmax = -INFINITY;
#pragma unroll
    for (int kf = 0; kf < 4; ++kf)
#pragma unroll
      for (int j = 0; j < 4; ++j) {
        float v = sc[kf][j] * SCL;
        if (edge) {
          int keyg = kb + kf * 16 + kgrp * 4 + j;
          if (keyg > qgs) v = -INFINITY;
        }
        sc[kf][j] = v;
        tmax = fmaxf(tmax, v);
      }
    tmax = fmaxf(tmax, __shfl_xor(tmax, 16));
    tmax = fmaxf(tmax, __shfl_xor(tmax, 32));
    // defer-rescale (T13): skip O/l rescale while max growth stays under 8 (log2 units)
    if (!__all(tmax <= mrun + 8.0f)) {
      const float mnew = fmaxf(mrun, tmax);
      const float corr = exp2f(mrun - mnew);
      lrun *= corr;
#pragma unroll
      for (int df = 0; df < 4; ++df) accS[df] *= corr;
      mrun = mnew;
    }
    float psum = 0.0f;
#pragma unroll
    for (int kf = 0; kf < 4; ++kf) {
      bf16x4 pv;
#pragma unroll
      for (int j = 0; j < 4; ++j) {
        float e = exp2f(sc[kf][j] - mrun);
        psum += e;
        pv[j] = (__bf16)e;  // v_cvt_pk_bf16_f32 pairs
      }
      pb[kf] = __builtin_bit_cast(s16x4, pv);
    }
    psum += __shfl_xor(psum, 16);
    psum += __shfl_xor(psum, 32);
    lrun += psum;
  };

  stage(0, 0);

  for (int kt = 0; kt <= qt[1]; ++kt) {
    const int kb = kt * 64;
    const int cur = kt & 1;
    // issue next tile's loads BEFORE waiting on this tile (counted vmcnt).
    // Hazard: stage(kt+1) writes buf[cur^1], last read during iter kt-1, sealed
    // by its trailing s_barrier.
    if (kt < qt[1]) {
      stage(kt + 1, cur ^ 1);
      asm volatile("s_waitcnt vmcnt(4)" ::: "memory");  // tile kt landed; kt+1 in flight
    } else {
      asm volatile("s_waitcnt vmcnt(0)" ::: "memory");
    }
    __builtin_amdgcn_sched_barrier(0);
    __builtin_amdgcn_s_barrier();
    __builtin_amdgcn_sched_barrier(0);

    s16x4 pb[2][4];
#pragma unroll
    for (int s = 0; s < 2; ++s)
      if (kt <= qt[s])
        proc(Kt[cur], qf0[s], qf1[s], mr[s], lr[s], accO[s], pb[s],
             kt == qt[s], qg[s], kb);

    // O^T += V^T @ P^T — V-frags shared by both q-sets
    const unsigned vb = vbase + (unsigned)cur * 8192u;
#pragma unroll
    for (int df = 0; df < 4; ++df) {
      unsigned a = vb + df * 2048;
      s16x4 vf0 = tr16<0>(a);
      s16x4 vf1 = tr16<512>(a);
      s16x4 vf2 = tr16<1024>(a);
      s16x4 vf3 = tr16<1536>(a);
      asm volatile("s_waitcnt lgkmcnt(0)" ::: "memory");
      __builtin_amdgcn_sched_barrier(0);
      __builtin_amdgcn_s_setprio(1);
#pragma unroll
      for (int s = 0; s < 2; ++s) {
        if (kt <= qt[s]) {
          accO[s][df] = mfma16(vf0, pb[s][0], accO[s][df]);
          accO[s][df] = mfma16(vf1, pb[s][1], accO[s][df]);
          accO[s][df] = mfma16(vf2, pb[s][2], accO[s][df]);
          accO[s][df] = mfma16(vf3, pb[s][3], accO[s][df]);
        }
      }
      __builtin_amdgcn_s_setprio(0);
    }

    __builtin_amdgcn_sched_barrier(0);
    __builtin_amdgcn_s_barrier();   // all reads of buf[cur] done before kt+2 overwrites
  }

#pragma unroll
  for (int s = 0; s < 2; ++s) {
    const float rl = 1.0f / lr[s];
    const size_t orow = (size_t)(bb * Sz + qg[s]) * Dz + hh * 64;
#pragma unroll
    for (int df = 0; df < 4; ++df) {
      s16x4 o;
#pragma unroll
      for (int j = 0; j < 4; ++j) o[j] = (short)f2bu(accO[s][df][j] * rl);
      *(s16x4*)&outA[orow + df * 16 + kgrp * 4] = o;
    }
  }
}

// ---------------- launch ----------------

extern "C" void kernel_launch(void* const* d_in, const int* in_sizes, int n_in,
                              void* d_out, int out_size, void* d_ws, size_t ws_size,
                              hipStream_t stream) {
  const float* x   = (const float*)d_in[0];
  // d_in[1] = mask (causal, known) — unused
  const float* wq  = (const float*)d_in[2];
  const float* wk  = (const float*)d_in[3];
  const float* wv  = (const float*)d_in[4];
  const float* wo  = (const float*)d_in[5];
  const float* w1  = (const float*)d_in[6];
  const float* b1  = (const float*)d_in[7];
  const float* w2  = (const float*)d_in[8];
  const float* b2  = (const float*)d_in[9];
  const float* g1  = (const float*)d_in[10];
  const float* be1 = (const float*)d_in[11];
  const float* g2  = (const float*)d_in[12];
  const float* be2 = (const float*)d_in[13];
  float* out = (float*)d_out;

  char* ws = (char*)d_ws;
  unsigned short* WqkvT = (unsigned short*)(ws);
  unsigned short* WoT   = (unsigned short*)(ws + 6291456);
  unsigned short* W1T   = (unsigned short*)(ws + 8388608);
  unsigned short* W2T   = (unsigned short*)(ws + 16777216);
  unsigned short* hbuf  = (unsigned short*)(ws + 25165824);
  unsigned short* big   = (unsigned short*)(ws + 41943040);  // QKV, later ff1

  dim3 tb(32, 8);
  pack_qkv<<<768, 256, 0, stream>>>(wq, wk, wv, WqkvT);
  transpose_f32_to_bf16<<<dim3(32, 32), tb, 0, stream>>>(wo, WoT, 1024, 1024);
  transpose_f32_to_bf16<<<dim3(128, 32), tb, 0, stream>>>(w1, W1T, 1024, 4096);
  transpose_f32_to_bf16<<<dim3(32, 128), tb, 0, stream>>>(w2, W2T, 4096, 1024);

  ln_kernel<<<Mz, 256, 0, stream>>>(x, g1, be1, hbuf);
  gemm256<128, EPI_BF16><<<768, 512, 0, stream>>>(
      hbuf, WqkvT, Mz, 3072, 1024, nullptr, nullptr, big, nullptr);
  attn_kernel<<<dim3(16, 16, 4), 256, 0, stream>>>(big, hbuf);
  gemm256<128, EPI_RES_F32><<<256, 512, 0, stream>>>(
      hbuf, WoT, Mz, 1024, 1024, nullptr, x, nullptr, out);
  ln_kernel<<<Mz, 256, 0, stream>>>(out, g2, be2, hbuf);
  gemm256<256, EPI_GELU_BF16><<<512, 512, 0, stream>>>(
      hbuf, W1T, Mz, Fz, 1024, b1, nullptr, big, nullptr);
  gemm256<128, EPI_BIAS_RES_F32><<<256, 512, 0, stream>>>(
      big, W2T, Mz, 1024, Fz, b2, out, nullptr, out);
}

// Round 13
// 429.792 us; speedup vs baseline: 1.1564x; 1.0558x over previous
//
#include <hip/hip_runtime.h>
#include <hip/hip_bf16.h>
#include <math.h>

// GPT decoder layer, MI355X/gfx950. bf16 MFMA GEMMs + fused flash attention.
// B=4 S=2048 D=1024 H=16 DH=64 F=4096.  Workspace layout (bytes):
//   [0,6M)      WqkvT  bf16 [3072][1024]   (pre-transposed, k-contiguous)
//   [6M,8M)     WoT    bf16 [1024][1024]
//   [8M,16M)    W1T    bf16 [4096][1024]
//   [16M,24M)   W2T    bf16 [1024][4096]
//   [24M,40M)   hbuf   bf16 [8192][1024]   (h -> attn_out -> h2, reused)
//   [40M,104M)  big    bf16                (QKV [8192][3072], later ff1 [8192][4096])

#define Bz 4
#define Sz 2048
#define Dz 1024
#define Hz 16
#define DHz 64
#define Fz 4096
#define Mz 8192

typedef float f32x4 __attribute__((ext_vector_type(4)));
typedef __bf16 bf16x8 __attribute__((ext_vector_type(8)));
typedef __bf16 bf16x4 __attribute__((ext_vector_type(4)));
typedef short s16x4 __attribute__((ext_vector_type(4)));

#define GLOAD_LDS16(g, l)                                                                   \
  __builtin_amdgcn_global_load_lds((const __attribute__((address_space(1))) unsigned int*)(g), \
                                   (__attribute__((address_space(3))) unsigned int*)(l), 16, 0, 0)

static __device__ __forceinline__ unsigned short f2bu(float f) {
  unsigned int u = __float_as_uint(f);
  u += 0x7fffu + ((u >> 16) & 1u);   // RNE to bf16
  return (unsigned short)(u >> 16);
}

static __device__ __forceinline__ f32x4 mfma32(bf16x8 a, bf16x8 b, f32x4 c) {
  return __builtin_amdgcn_mfma_f32_16x16x32_bf16(a, b, c, 0, 0, 0);
}
static __device__ __forceinline__ f32x4 mfma16(s16x4 a, s16x4 b, f32x4 c) {
#if __has_builtin(__builtin_amdgcn_mfma_f32_16x16x16bf16_1k)
  return __builtin_amdgcn_mfma_f32_16x16x16bf16_1k(a, b, c, 0, 0, 0);
#else
  asm("v_mfma_f32_16x16x16_bf16 %0, %1, %2, %0" : "+v"(c) : "v"(a), "v"(b));
  return c;
#endif
}

// hardware transpose read: lane l elem j <- lds[base + (l&15) + j*16 + (l>>4)*64] (bf16 elems)
template <int OFF>
static __device__ __forceinline__ s16x4 tr16(unsigned addr) {
  s16x4 r;
  asm volatile("ds_read_b64_tr_b16 %0, %1 offset:%2" : "=v"(r) : "v"(addr), "i"(OFF));
  return r;
}

// ---------------- weight packing ----------------

__global__ __launch_bounds__(256) void pack_qkv(
    const float* __restrict__ wq, const float* __restrict__ wk, const float* __restrict__ wv,
    unsigned short* __restrict__ outW)  // [3072][1024], row n = proj*1024 + h*64 + e, col = d
{
  __shared__ float tile[64][65];
  const int blk = blockIdx.x;       // 768 = 16 dchunk x 16 h x 3 proj
  const int dc = blk & 15;
  const int h  = (blk >> 4) & 15;
  const int p  = blk >> 8;
  const float* w = p == 0 ? wq : (p == 1 ? wk : wv);
  const int tid = threadIdx.x;
#pragma unroll
  for (int i = 0; i < 4; ++i) {
    int idx = i * 256 + tid;
    int dl = idx >> 4;
    int e0 = (idx & 15) * 4;
    const float4 v = *(const float4*)&w[(size_t)(h * 1024 + dc * 64 + dl) * 64 + e0];
    tile[dl][e0 + 0] = v.x; tile[dl][e0 + 1] = v.y;
    tile[dl][e0 + 2] = v.z; tile[dl][e0 + 3] = v.w;
  }
  __syncthreads();
#pragma unroll
  for (int i = 0; i < 4; ++i) {
    int idx = i * 256 + tid;
    int e = idx >> 4;
    int d0 = (idx & 15) * 4;
    ushort4 o;
    o.x = f2bu(tile[d0 + 0][e]); o.y = f2bu(tile[d0 + 1][e]);
    o.z = f2bu(tile[d0 + 2][e]); o.w = f2bu(tile[d0 + 3][e]);
    *(ushort4*)&outW[(size_t)(p * 1024 + h * 64 + e) * 1024 + dc * 64 + d0] = o;
  }
}

__global__ __launch_bounds__(256) void transpose_f32_to_bf16(
    const float* __restrict__ in, unsigned short* __restrict__ out, int R, int C)
{ // in [R][C] fp32 -> out [C][R] bf16
  __shared__ float tile[32][33];
  int c0 = blockIdx.x * 32, r0 = blockIdx.y * 32;
  int x = threadIdx.x, y = threadIdx.y;
#pragma unroll
  for (int i = 0; i < 32; i += 8)
    tile[y + i][x] = in[(size_t)(r0 + y + i) * C + c0 + x];
  __syncthreads();
#pragma unroll
  for (int i = 0; i < 32; i += 8)
    out[(size_t)(c0 + y + i) * R + r0 + x] = f2bu(tile[x][y + i]);
}

// ---------------- layernorm ----------------

__global__ __launch_bounds__(256) void ln_kernel(
    const float* __restrict__ x, const float* __restrict__ gamma, const float* __restrict__ beta,
    unsigned short* __restrict__ outH)
{
  const int row = blockIdx.x;
  const int tid = threadIdx.x;
  const float4 v = ((const float4*)(x + (size_t)row * Dz))[tid];
  float s = v.x + v.y + v.z + v.w;
  float s2 = v.x * v.x + v.y * v.y + v.z * v.z + v.w * v.w;
#pragma unroll
  for (int o = 32; o > 0; o >>= 1) {
    s += __shfl_xor(s, o);
    s2 += __shfl_xor(s2, o);
  }
  __shared__ float ss[4], ss2[4];
  if ((tid & 63) == 0) { ss[tid >> 6] = s; ss2[tid >> 6] = s2; }
  __syncthreads();
  s = ss[0] + ss[1] + ss[2] + ss[3];
  s2 = ss2[0] + ss2[1] + ss2[2] + ss2[3];
  const float mean = s * (1.0f / Dz);
  const float rstd = rsqrtf(s2 * (1.0f / Dz) - mean * mean + 1e-5f);
  const float4 g4 = ((const float4*)gamma)[tid];
  const float4 b4 = ((const float4*)beta)[tid];
  ushort4 o;
  o.x = f2bu((v.x - mean) * rstd * g4.x + b4.x);
  o.y = f2bu((v.y - mean) * rstd * g4.y + b4.y);
  o.z = f2bu((v.z - mean) * rstd * g4.z + b4.z);
  o.w = f2bu((v.w - mean) * rstd * g4.w + b4.w);
  ((ushort4*)(outH + (size_t)row * Dz))[tid] = o;
}

// ---------------- GEMM m97-structure: 128x128, BK=32, 256 thr / 4 waves ----------------
// C[M,N] = A[M,K](bf16) @ BT[N,K]^T(bf16).
// R12 synthesis: all 512-thread/1-block-per-CU variants (R4-R11) plateau at
// ~600-700 TF regardless of schedule. The measured tile-space winner at the
// simple 2-barrier structure is the m97 128^2 / 4-wave shape (912 TF at 4096^3;
// 128x256=823, 256^2=792) whose hiding mechanism is 3 blocks/CU cross-block
// overlap (m114) - structurally impossible at 512 threads + >96KB LDS.
// R0's version of this shape ran ~590 TF due to (a) the (row&3) swizzle bug
// (64B rows -> 4-way conflicts, R8's 6.3M counter) and (b) no XCD swizzle.
// Fixes: (row>>1)&3 swizzle (R11: measured 0 conflicts) + bijective XCD swizzle.
// Single 16KB LDS buffer, plain __syncthreads staging (m99/m100: explicit dbuf
// neutral here), unpinned compute (m141/R9), __launch_bounds__(256,3).

enum { EPI_BF16 = 0, EPI_GELU_BF16 = 1, EPI_RES_F32 = 2, EPI_BIAS_RES_F32 = 3 };

template <int EPI>
__global__ __launch_bounds__(256, 3) void gemm128(
    const unsigned short* __restrict__ A,   // [M,K] bf16
    const unsigned short* __restrict__ BT,  // [N,K] bf16
    int M, int N, int K,
    const float* bias, const float* resid,  // resid/outf may alias: no __restrict__
    unsigned short* outb, float* outf)
{
  __shared__ unsigned short As[128 * 32];  // [row][32k], 16B chunks, (row>>1)&3 XOR
  __shared__ unsigned short Bs[128 * 32];
  const int tid = threadIdx.x;
  const int lane = tid & 63;
  const int wid = tid >> 6;
  const int wm = (wid >> 1) * 64;
  const int wn = (wid & 1) * 64;
  const int rsel = lane & 15;
  const int kgrp = lane >> 4;

  // XCD-chunked bijective swizzle (nwg % 8 == 0 for all our grids)
  const int nwg = gridDim.x;
  const int bid = blockIdx.x;
  const int id2 = (bid & 7) * (nwg >> 3) + (bid >> 3);
  const int nbx = N / 128;
  const int n0 = (id2 % nbx) * 128;
  const int m0 = (id2 / nbx) * 128;

  f32x4 acc[4][4] = {};

  const int T = K >> 5;
  for (int t = 0; t < T; ++t) {
    if (t) __syncthreads();
    const int kOff = t * 32;
#pragma unroll
    for (int r = 0; r < 2; ++r) {          // 512 chunks of 16B per matrix tile
      int gc = r * 256 + tid;
      int row = gc >> 2;
      int kcs = (gc & 3) ^ ((row >> 1) & 3);   // corrected swizzle (128B span)
      GLOAD_LDS16(A + (size_t)(m0 + row) * K + kOff + kcs * 8, &As[gc * 8]);
      GLOAD_LDS16(BT + (size_t)(n0 + row) * K + kOff + kcs * 8, &Bs[gc * 8]);
    }
    __syncthreads();
    bf16x8 af[4], bfr[4];
#pragma unroll
    for (int mf = 0; mf < 4; ++mf) {
      int ar = wm + mf * 16 + rsel;
      af[mf] = *(const bf16x8*)&As[ar * 32 + ((kgrp ^ ((ar >> 1) & 3)) * 8)];
    }
#pragma unroll
    for (int nf = 0; nf < 4; ++nf) {
      int br = wn + nf * 16 + rsel;
      bfr[nf] = *(const bf16x8*)&Bs[br * 32 + ((kgrp ^ ((br >> 1) & 3)) * 8)];
    }
    // unpinned: compiler emits fine-grained lgkmcnt and co-schedules with MFMA
#pragma unroll
    for (int mf = 0; mf < 4; ++mf)
#pragma unroll
      for (int nf = 0; nf < 4; ++nf)
        acc[mf][nf] = mfma32(af[mf], bfr[nf], acc[mf][nf]);
  }

#pragma unroll
  for (int mf = 0; mf < 4; ++mf) {
#pragma unroll
    for (int nf = 0; nf < 4; ++nf) {
      const int n = n0 + wn + nf * 16 + rsel;
#pragma unroll
      for (int j = 0; j < 4; ++j) {
        const int m = m0 + wm + mf * 16 + kgrp * 4 + j;
        const size_t idx = (size_t)m * N + n;
        float v = acc[mf][nf][j];
        if constexpr (EPI == EPI_BF16) {
          outb[idx] = f2bu(v);
        } else if constexpr (EPI == EPI_GELU_BF16) {
          v += bias[n];
          v = 0.5f * v * (1.0f + erff(v * 0.70710678118654752f));
          outb[idx] = f2bu(v);
        } else if constexpr (EPI == EPI_RES_F32) {
          outf[idx] = v + resid[idx];
        } else {
          outf[idx] = v + bias[n] + resid[idx];
        }
      }
    }
  }
}

// ---------------- fused causal flash attention (R9-exact, best measured) ----------
// Block = PAIR of q-tiles {i, 31-i} x head x batch, grid 1024 = 4 blocks/CU.
// S^T = K @ Q^T via mfma 16x16x32; P^T stays in registers as the B-frag of
// mfma 16x16x16 for O^T = V^T @ P^T; V read with ds_read_b64_tr_b16, V-frags
// shared by both q-sets. Softmax in log2 domain with defer-rescale (THR=8).
// (R12's counted-vmcnt dbuf raised occupancy 20->34% but was time-neutral and
// grew FETCH 125->165MB -> reverted.)

__global__ __launch_bounds__(256, 4) void attn_kernel(
    const unsigned short* __restrict__ QKV,  // [Mz][3072] bf16 (q|k|v, feature h*64+e)
    unsigned short* __restrict__ outA)       // [Mz][Dz]  bf16
{
  __shared__ unsigned short Kt[64 * 64];  // [key][d], 16B d-chunk XOR-swizzled by key&7
  __shared__ unsigned short Vs[64 * 64];  // subtiled for tr16 reads
  const int pi = blockIdx.x;  // 0..15
  const int hh = blockIdx.y;
  const int bb = blockIdx.z;
  const int tid = threadIdx.x;
  const int lane = tid & 63;
  const int w = tid >> 6;
  const int rsel = lane & 15;
  const int kgrp = lane >> 4;
  const int qt[2] = {pi, 31 - pi};

  bf16x8 qf0[2], qf1[2];
  int qg[2];
#pragma unroll
  for (int s = 0; s < 2; ++s) {
    qg[s] = qt[s] * 64 + w * 16 + rsel;
    const size_t rowQ = (size_t)(bb * Sz + qg[s]) * 3072 + hh * 64;
    qf0[s] = *(const bf16x8*)&QKV[rowQ + kgrp * 8];
    qf1[s] = *(const bf16x8*)&QKV[rowQ + 32 + kgrp * 8];
  }

  f32x4 accO[2][4] = {};  // [set][df]; O^T row=d=(df*16+kgrp*4+j), col=q=rsel
  float mr[2] = {-INFINITY, -INFINITY};
  float lr[2] = {0.0f, 0.0f};

  auto vs3 = (__attribute__((address_space(3))) unsigned short*)Vs;
  const unsigned vbase = (unsigned)(uintptr_t)vs3 + (unsigned)lane * 8u;
  constexpr float SCL = 0.18033688011112042f;  // log2(e)/sqrt(64)

  // S^T + online softmax (log2 domain, defer-rescale) -> P^T bf16 B-frags
  auto proc = [&](const bf16x8& q0, const bf16x8& q1, float& mrun, float& lrun,
                  f32x4* accS, s16x4* pb, bool edge, int qgs, int kb) {
    f32x4 sc[4];
    __builtin_amdgcn_s_setprio(1);
#pragma unroll
    for (int kf = 0; kf < 4; ++kf) {
      int key = kf * 16 + rsel;
      bf16x8 k0 = *(const bf16x8*)&Kt[key * 64 + ((kgrp ^ (key & 7)) * 8)];
      bf16x8 k1 = *(const bf16x8*)&Kt[key * 64 + (((4 + kgrp) ^ (key & 7)) * 8)];
      f32x4 s = {};
      s = mfma32(k0, q0, s);
      s = mfma32(k1, q1, s);
      sc[kf] = s;
    }
    __builtin_amdgcn_s_setprio(0);
    float tmax = -INFINITY;
#pragma unroll
    for (int kf = 0; kf < 4; ++kf)
#pragma unroll
      for (int j = 0; j < 4; ++j) {
        float v = sc[kf][j] * SCL;
        if (edge) {
          int keyg = kb + kf * 16 + kgrp * 4 + j;
          if (keyg > qgs) v = -INFINITY;
        }
        sc[kf][j] = v;
        tmax = fmaxf(tmax, v);
      }
    tmax = fmaxf(tmax, __shfl_xor(tmax, 16));
    tmax = fmaxf(tmax, __shfl_xor(tmax, 32));
    // defer-rescale (T13): skip O/l rescale while max growth stays under 8 (log2 units)
    if (!__all(tmax <= mrun + 8.0f)) {
      const float mnew = fmaxf(mrun, tmax);
      const float corr = exp2f(mrun - mnew);
      lrun *= corr;
#pragma unroll
      for (int df = 0; df < 4; ++df) accS[df] *= corr;
      mrun = mnew;
    }
    float psum = 0.0f;
#pragma unroll
    for (int kf = 0; kf < 4; ++kf) {
      bf16x4 pv;
#pragma unroll
      for (int j = 0; j < 4; ++j) {
        float e = exp2f(sc[kf][j] - mrun);
        psum += e;
        pv[j] = (__bf16)e;  // v_cvt_pk_bf16_f32 pairs
      }
      pb[kf] = __builtin_bit_cast(s16x4, pv);
    }
    psum += __shfl_xor(psum, 16);
    psum += __shfl_xor(psum, 32);
    lrun += psum;
  };

  for (int kt = 0; kt <= qt[1]; ++kt) {
    const int kb = kt * 64;
    if (kt) __syncthreads();  // prev tile's LDS reads done before overwrite
    // stage K: LDS linear, global d-chunk XOR-swizzled by key&7
#pragma unroll
    for (int r = 0; r < 2; ++r) {
      int c = r * 256 + tid;
      int key = c >> 3;
      int dcs = (c & 7) ^ (key & 7);
      GLOAD_LDS16(QKV + (size_t)(bb * Sz + kb + key) * 3072 + 1024 + hh * 64 + dcs * 8,
                  &Kt[c * 8]);
    }
    // stage V: LDS linear; source permuted so LDS holds subtiled layout
#pragma unroll
    for (int r = 0; r < 2; ++r) {
      int c = r * 256 + tid;
      int key = ((c >> 3) & 15) * 4 + ((c >> 1) & 3);
      int d = (c >> 7) * 16 + (c & 1) * 8;
      GLOAD_LDS16(QKV + (size_t)(bb * Sz + kb + key) * 3072 + 2048 + hh * 64 + d,
                  &Vs[c * 8]);
    }
    __syncthreads();

    s16x4 pb[2][4];
#pragma unroll
    for (int s = 0; s < 2; ++s)
      if (kt <= qt[s])
        proc(qf0[s], qf1[s], mr[s], lr[s], accO[s], pb[s], kt == qt[s], qg[s], kb);

    // O^T += V^T @ P^T — V-frags shared by both q-sets
#pragma unroll
    for (int df = 0; df < 4; ++df) {
      unsigned a = vbase + df * 2048;
      s16x4 vf0 = tr16<0>(a);
      s16x4 vf1 = tr16<512>(a);
      s16x4 vf2 = tr16<1024>(a);
      s16x4 vf3 = tr16<1536>(a);
      asm volatile("s_waitcnt lgkmcnt(0)" ::: "memory");
      __builtin_amdgcn_sched_barrier(0);
      __builtin_amdgcn_s_setprio(1);
#pragma unroll
      for (int s = 0; s < 2; ++s) {
        if (kt <= qt[s]) {
          accO[s][df] = mfma16(vf0, pb[s][0], accO[s][df]);
          accO[s][df] = mfma16(vf1, pb[s][1], accO[s][df]);
          accO[s][df] = mfma16(vf2, pb[s][2], accO[s][df]);
          accO[s][df] = mfma16(vf3, pb[s][3], accO[s][df]);
        }
      }
      __builtin_amdgcn_s_setprio(0);
    }
  }

#pragma unroll
  for (int s = 0; s < 2; ++s) {
    const float rl = 1.0f / lr[s];
    const size_t orow = (size_t)(bb * Sz + qg[s]) * Dz + hh * 64;
#pragma unroll
    for (int df = 0; df < 4; ++df) {
      s16x4 o;
#pragma unroll
      for (int j = 0; j < 4; ++j) o[j] = (short)f2bu(accO[s][df][j] * rl);
      *(s16x4*)&outA[orow + df * 16 + kgrp * 4] = o;
    }
  }
}

// ---------------- launch ----------------

extern "C" void kernel_launch(void* const* d_in, const int* in_sizes, int n_in,
                              void* d_out, int out_size, void* d_ws, size_t ws_size,
                              hipStream_t stream) {
  const float* x   = (const float*)d_in[0];
  // d_in[1] = mask (causal, known) — unused
  const float* wq  = (const float*)d_in[2];
  const float* wk  = (const float*)d_in[3];
  const float* wv  = (const float*)d_in[4];
  const float* wo  = (const float*)d_in[5];
  const float* w1  = (const float*)d_in[6];
  const float* b1  = (const float*)d_in[7];
  const float* w2  = (const float*)d_in[8];
  const float* b2  = (const float*)d_in[9];
  const float* g1  = (const float*)d_in[10];
  const float* be1 = (const float*)d_in[11];
  const float* g2  = (const float*)d_in[12];
  const float* be2 = (const float*)d_in[13];
  float* out = (float*)d_out;

  char* ws = (char*)d_ws;
  unsigned short* WqkvT = (unsigned short*)(ws);
  unsigned short* WoT   = (unsigned short*)(ws + 6291456);
  unsigned short* W1T   = (unsigned short*)(ws + 8388608);
  unsigned short* W2T   = (unsigned short*)(ws + 16777216);
  unsigned short* hbuf  = (unsigned short*)(ws + 25165824);
  unsigned short* big   = (unsigned short*)(ws + 41943040);  // QKV, later ff1

  dim3 tb(32, 8);
  pack_qkv<<<768, 256, 0, stream>>>(wq, wk, wv, WqkvT);
  transpose_f32_to_bf16<<<dim3(32, 32), tb, 0, stream>>>(wo, WoT, 1024, 1024);
  transpose_f32_to_bf16<<<dim3(128, 32), tb, 0, stream>>>(w1, W1T, 1024, 4096);
  transpose_f32_to_bf16<<<dim3(32, 128), tb, 0, stream>>>(w2, W2T, 4096, 1024);

  ln_kernel<<<Mz, 256, 0, stream>>>(x, g1, be1, hbuf);
  gemm128<EPI_BF16><<<1536, 256, 0, stream>>>(
      hbuf, WqkvT, Mz, 3072, 1024, nullptr, nullptr, big, nullptr);
  attn_kernel<<<dim3(16, 16, 4), 256, 0, stream>>>(big, hbuf);
  gemm128<EPI_RES_F32><<<512, 256, 0, stream>>>(
      hbuf, WoT, Mz, 1024, 1024, nullptr, x, nullptr, out);
  ln_kernel<<<Mz, 256, 0, stream>>>(out, g2, be2, hbuf);
  gemm128<EPI_GELU_BF16><<<2048, 256, 0, stream>>>(
      hbuf, W1T, Mz, Fz, 1024, b1, nullptr, big, nullptr);
  gemm128<EPI_BIAS_RES_F32><<<512, 256, 0, stream>>>(
      big, W2T, Mz, 1024, Fz, b2, out, nullptr, out);
}

// Round 14
// 421.274 us; speedup vs baseline: 1.1798x; 1.0202x over previous
//
#include <hip/hip_runtime.h>
#include <hip/hip_bf16.h>
#include <math.h>

// GPT decoder layer, MI355X/gfx950. bf16 MFMA GEMMs + fused flash attention.
// B=4 S=2048 D=1024 H=16 DH=64 F=4096.  Workspace layout (bytes):
//   [0,6M)      WqkvT  bf16 [3072][1024]   (pre-transposed, k-contiguous)
//   [6M,8M)     WoT    bf16 [1024][1024]
//   [8M,16M)    W1T    bf16 [4096][1024]
//   [16M,24M)   W2T    bf16 [1024][4096]
//   [24M,40M)   hbuf   bf16 [8192][1024]   (h -> attn_out -> h2, reused)
//   [40M,104M)  big    bf16                (QKV [8192][3072], later ff1 [8192][4096])

#define Bz 4
#define Sz 2048
#define Dz 1024
#define Hz 16
#define DHz 64
#define Fz 4096
#define Mz 8192

typedef float f32x4 __attribute__((ext_vector_type(4)));
typedef __bf16 bf16x8 __attribute__((ext_vector_type(8)));
typedef __bf16 bf16x4 __attribute__((ext_vector_type(4)));
typedef short s16x4 __attribute__((ext_vector_type(4)));

#define GLOAD_LDS16(g, l)                                                                   \
  __builtin_amdgcn_global_load_lds((const __attribute__((address_space(1))) unsigned int*)(g), \
                                   (__attribute__((address_space(3))) unsigned int*)(l), 16, 0, 0)

static __device__ __forceinline__ unsigned short f2bu(float f) {
  unsigned int u = __float_as_uint(f);
  u += 0x7fffu + ((u >> 16) & 1u);   // RNE to bf16
  return (unsigned short)(u >> 16);
}

static __device__ __forceinline__ f32x4 mfma32(bf16x8 a, bf16x8 b, f32x4 c) {
  return __builtin_amdgcn_mfma_f32_16x16x32_bf16(a, b, c, 0, 0, 0);
}
static __device__ __forceinline__ f32x4 mfma16(s16x4 a, s16x4 b, f32x4 c) {
#if __has_builtin(__builtin_amdgcn_mfma_f32_16x16x16bf16_1k)
  return __builtin_amdgcn_mfma_f32_16x16x16bf16_1k(a, b, c, 0, 0, 0);
#else
  asm("v_mfma_f32_16x16x16_bf16 %0, %1, %2, %0" : "+v"(c) : "v"(a), "v"(b));
  return c;
#endif
}

// hardware transpose read: lane l elem j <- lds[base + (l&15) + j*16 + (l>>4)*64] (bf16 elems)
template <int OFF>
static __device__ __forceinline__ s16x4 tr16(unsigned addr) {
  s16x4 r;
  asm volatile("ds_read_b64_tr_b16 %0, %1 offset:%2" : "=v"(r) : "v"(addr), "i"(OFF));
  return r;
}

// ---------------- weight packing ----------------

__global__ __launch_bounds__(256) void pack_qkv(
    const float* __restrict__ wq, const float* __restrict__ wk, const float* __restrict__ wv,
    unsigned short* __restrict__ outW)  // [3072][1024], row n = proj*1024 + h*64 + e, col = d
{
  __shared__ float tile[64][65];
  const int blk = blockIdx.x;       // 768 = 16 dchunk x 16 h x 3 proj
  const int dc = blk & 15;
  const int h  = (blk >> 4) & 15;
  const int p  = blk >> 8;
  const float* w = p == 0 ? wq : (p == 1 ? wk : wv);
  const int tid = threadIdx.x;
#pragma unroll
  for (int i = 0; i < 4; ++i) {
    int idx = i * 256 + tid;
    int dl = idx >> 4;
    int e0 = (idx & 15) * 4;
    const float4 v = *(const float4*)&w[(size_t)(h * 1024 + dc * 64 + dl) * 64 + e0];
    tile[dl][e0 + 0] = v.x; tile[dl][e0 + 1] = v.y;
    tile[dl][e0 + 2] = v.z; tile[dl][e0 + 3] = v.w;
  }
  __syncthreads();
#pragma unroll
  for (int i = 0; i < 4; ++i) {
    int idx = i * 256 + tid;
    int e = idx >> 4;
    int d0 = (idx & 15) * 4;
    ushort4 o;
    o.x = f2bu(tile[d0 + 0][e]); o.y = f2bu(tile[d0 + 1][e]);
    o.z = f2bu(tile[d0 + 2][e]); o.w = f2bu(tile[d0 + 3][e]);
    *(ushort4*)&outW[(size_t)(p * 1024 + h * 64 + e) * 1024 + dc * 64 + d0] = o;
  }
}

__global__ __launch_bounds__(256) void transpose_f32_to_bf16(
    const float* __restrict__ in, unsigned short* __restrict__ out, int R, int C)
{ // in [R][C] fp32 -> out [C][R] bf16
  __shared__ float tile[32][33];
  int c0 = blockIdx.x * 32, r0 = blockIdx.y * 32;
  int x = threadIdx.x, y = threadIdx.y;
#pragma unroll
  for (int i = 0; i < 32; i += 8)
    tile[y + i][x] = in[(size_t)(r0 + y + i) * C + c0 + x];
  __syncthreads();
#pragma unroll
  for (int i = 0; i < 32; i += 8)
    out[(size_t)(c0 + y + i) * R + r0 + x] = f2bu(tile[x][y + i]);
}

// ---------------- layernorm ----------------

__global__ __launch_bounds__(256) void ln_kernel(
    const float* __restrict__ x, const float* __restrict__ gamma, const float* __restrict__ beta,
    unsigned short* __restrict__ outH)
{
  const int row = blockIdx.x;
  const int tid = threadIdx.x;
  const float4 v = ((const float4*)(x + (size_t)row * Dz))[tid];
  float s = v.x + v.y + v.z + v.w;
  float s2 = v.x * v.x + v.y * v.y + v.z * v.z + v.w * v.w;
#pragma unroll
  for (int o = 32; o > 0; o >>= 1) {
    s += __shfl_xor(s, o);
    s2 += __shfl_xor(s2, o);
  }
  __shared__ float ss[4], ss2[4];
  if ((tid & 63) == 0) { ss[tid >> 6] = s; ss2[tid >> 6] = s2; }
  __syncthreads();
  s = ss[0] + ss[1] + ss[2] + ss[3];
  s2 = ss2[0] + ss2[1] + ss2[2] + ss2[3];
  const float mean = s * (1.0f / Dz);
  const float rstd = rsqrtf(s2 * (1.0f / Dz) - mean * mean + 1e-5f);
  const float4 g4 = ((const float4*)gamma)[tid];
  const float4 b4 = ((const float4*)beta)[tid];
  ushort4 o;
  o.x = f2bu((v.x - mean) * rstd * g4.x + b4.x);
  o.y = f2bu((v.y - mean) * rstd * g4.y + b4.y);
  o.z = f2bu((v.z - mean) * rstd * g4.z + b4.z);
  o.w = f2bu((v.w - mean) * rstd * g4.w + b4.w);
  ((ushort4*)(outH + (size_t)row * Dz))[tid] = o;
}

// ---------------- GEMM m97-structure: 128x128, BK=64, 256 thr / 4 waves, 4 blk/CU ----
// C[M,N] = A[M,K](bf16) @ BT[N,K]^T(bf16).
// R13 (m97-shape, BK=32, 3 blk/CU) = 429.8us best; FFN1 106us @ MfmaUtil 28%,
// occ 39%, VGPR 56 (+64 AGPR = 120 unified regs). This round, same mechanism
// deeper: (a) BK=64 halves the barrier count (32 -> 16 iters for K=1024) using
// the R9-proven (row&7)/128B-span XOR swizzle (measured 0 conflicts); (b)
// __launch_bounds__(256,4): 120 regs <= 128 and 4 x 32KB = 128KB LDS <= 160KB
// -> 4 blocks/CU of cross-block overlap (m114) to hide the staging drain.
// Single-buffered, plain __syncthreads staging (m99/m100: explicit dbuf is
// neutral at this structure), unpinned compute (m141/R9).

enum { EPI_BF16 = 0, EPI_GELU_BF16 = 1, EPI_RES_F32 = 2, EPI_BIAS_RES_F32 = 3 };

template <int EPI>
__global__ __launch_bounds__(256, 4) void gemm128(
    const unsigned short* __restrict__ A,   // [M,K] bf16
    const unsigned short* __restrict__ BT,  // [N,K] bf16
    int M, int N, int K,
    const float* bias, const float* resid,  // resid/outf may alias: no __restrict__
    unsigned short* outb, float* outf)
{
  constexpr int BK = 64;
  __shared__ unsigned short As[128 * BK];  // [row][64k], 16B chunks, (row&7) XOR
  __shared__ unsigned short Bs[128 * BK];
  const int tid = threadIdx.x;
  const int lane = tid & 63;
  const int wid = tid >> 6;
  const int wm = (wid >> 1) * 64;
  const int wn = (wid & 1) * 64;
  const int rsel = lane & 15;
  const int kgrp = lane >> 4;

  // XCD-chunked bijective swizzle (nwg % 8 == 0 for all our grids)
  const int nwg = gridDim.x;
  const int bid = blockIdx.x;
  const int id2 = (bid & 7) * (nwg >> 3) + (bid >> 3);
  const int nbx = N / 128;
  const int n0 = (id2 % nbx) * 128;
  const int m0 = (id2 / nbx) * 128;

  f32x4 acc[4][4] = {};

  const int T = K >> 6;
  for (int t = 0; t < T; ++t) {
    if (t) __syncthreads();
    const int kOff = t * BK;
#pragma unroll
    for (int r = 0; r < 4; ++r) {          // 1024 chunks of 16B per matrix tile
      int gc = r * 256 + tid;
      int row = gc >> 3;
      int kcs = (gc & 7) ^ (row & 7);      // proven 128B-span swizzle (0 conflicts)
      GLOAD_LDS16(A + (size_t)(m0 + row) * K + kOff + kcs * 8, &As[gc * 8]);
      GLOAD_LDS16(BT + (size_t)(n0 + row) * K + kOff + kcs * 8, &Bs[gc * 8]);
    }
    __syncthreads();
#pragma unroll
    for (int kk = 0; kk < 2; ++kk) {
      bf16x8 af[4], bfr[4];
#pragma unroll
      for (int mf = 0; mf < 4; ++mf) {
        int ar = wm + mf * 16 + rsel;
        af[mf] = *(const bf16x8*)&As[ar * BK + (((kk * 4 + kgrp) ^ (ar & 7)) * 8)];
      }
#pragma unroll
      for (int nf = 0; nf < 4; ++nf) {
        int br = wn + nf * 16 + rsel;
        bfr[nf] = *(const bf16x8*)&Bs[br * BK + (((kk * 4 + kgrp) ^ (br & 7)) * 8)];
      }
      // unpinned: compiler emits fine-grained lgkmcnt and co-schedules with MFMA
#pragma unroll
      for (int mf = 0; mf < 4; ++mf)
#pragma unroll
        for (int nf = 0; nf < 4; ++nf)
          acc[mf][nf] = mfma32(af[mf], bfr[nf], acc[mf][nf]);
    }
  }

#pragma unroll
  for (int mf = 0; mf < 4; ++mf) {
#pragma unroll
    for (int nf = 0; nf < 4; ++nf) {
      const int n = n0 + wn + nf * 16 + rsel;
#pragma unroll
      for (int j = 0; j < 4; ++j) {
        const int m = m0 + wm + mf * 16 + kgrp * 4 + j;
        const size_t idx = (size_t)m * N + n;
        float v = acc[mf][nf][j];
        if constexpr (EPI == EPI_BF16) {
          outb[idx] = f2bu(v);
        } else if constexpr (EPI == EPI_GELU_BF16) {
          v += bias[n];
          v = 0.5f * v * (1.0f + erff(v * 0.70710678118654752f));
          outb[idx] = f2bu(v);
        } else if constexpr (EPI == EPI_RES_F32) {
          outf[idx] = v + resid[idx];
        } else {
          outf[idx] = v + bias[n] + resid[idx];
        }
      }
    }
  }
}

// ---------------- fused causal flash attention (R9-exact, best measured) ----------
// Block = PAIR of q-tiles {i, 31-i} x head x batch, grid 1024 = 4 blocks/CU.
// S^T = K @ Q^T via mfma 16x16x32; P^T stays in registers as the B-frag of
// mfma 16x16x16 for O^T = V^T @ P^T; V read with ds_read_b64_tr_b16, V-frags
// shared by both q-sets. Softmax in log2 domain with defer-rescale (THR=8).

__global__ __launch_bounds__(256, 4) void attn_kernel(
    const unsigned short* __restrict__ QKV,  // [Mz][3072] bf16 (q|k|v, feature h*64+e)
    unsigned short* __restrict__ outA)       // [Mz][Dz]  bf16
{
  __shared__ unsigned short Kt[64 * 64];  // [key][d], 16B d-chunk XOR-swizzled by key&7
  __shared__ unsigned short Vs[64 * 64];  // subtiled for tr16 reads
  const int pi = blockIdx.x;  // 0..15
  const int hh = blockIdx.y;
  const int bb = blockIdx.z;
  const int tid = threadIdx.x;
  const int lane = tid & 63;
  const int w = tid >> 6;
  const int rsel = lane & 15;
  const int kgrp = lane >> 4;
  const int qt[2] = {pi, 31 - pi};

  bf16x8 qf0[2], qf1[2];
  int qg[2];
#pragma unroll
  for (int s = 0; s < 2; ++s) {
    qg[s] = qt[s] * 64 + w * 16 + rsel;
    const size_t rowQ = (size_t)(bb * Sz + qg[s]) * 3072 + hh * 64;
    qf0[s] = *(const bf16x8*)&QKV[rowQ + kgrp * 8];
    qf1[s] = *(const bf16x8*)&QKV[rowQ + 32 + kgrp * 8];
  }

  f32x4 accO[2][4] = {};  // [set][df]; O^T row=d=(df*16+kgrp*4+j), col=q=rsel
  float mr[2] = {-INFINITY, -INFINITY};
  float lr[2] = {0.0f, 0.0f};

  auto vs3 = (__attribute__((address_space(3))) unsigned short*)Vs;
  const unsigned vbase = (unsigned)(uintptr_t)vs3 + (unsigned)lane * 8u;
  constexpr float SCL = 0.18033688011112042f;  // log2(e)/sqrt(64)

  // S^T + online softmax (log2 domain, defer-rescale) -> P^T bf16 B-frags
  auto proc = [&](const bf16x8& q0, const bf16x8& q1, float& mrun, float& lrun,
                  f32x4* accS, s16x4* pb, bool edge, int qgs, int kb) {
    f32x4 sc[4];
    __builtin_amdgcn_s_setprio(1);
#pragma unroll
    for (int kf = 0; kf < 4; ++kf) {
      int key = kf * 16 + rsel;
      bf16x8 k0 = *(const bf16x8*)&Kt[key * 64 + ((kgrp ^ (key & 7)) * 8)];
      bf16x8 k1 = *(const bf16x8*)&Kt[key * 64 + (((4 + kgrp) ^ (key & 7)) * 8)];
      f32x4 s = {};
      s = mfma32(k0, q0, s);
      s = mfma32(k1, q1, s);
      sc[kf] = s;
    }
    __builtin_amdgcn_s_setprio(0);
    float tmax = -INFINITY;
#pragma unroll
    for (int kf = 0; kf < 4; ++kf)
#pragma unroll
      for (int j = 0; j < 4; ++j) {
        float v = sc[kf][j] * SCL;
        if (edge) {
          int keyg = kb + kf * 16 + kgrp * 4 + j;
          if (keyg > qgs) v = -INFINITY;
        }
        sc[kf][j] = v;
        tmax = fmaxf(tmax, v);
      }
    tmax = fmaxf(tmax, __shfl_xor(tmax, 16));
    tmax = fmaxf(tmax, __shfl_xor(tmax, 32));
    // defer-rescale (T13): skip O/l rescale while max growth stays under 8 (log2 units)
    if (!__all(tmax <= mrun + 8.0f)) {
      const float mnew = fmaxf(mrun, tmax);
      const float corr = exp2f(mrun - mnew);
      lrun *= corr;
#pragma unroll
      for (int df = 0; df < 4; ++df) accS[df] *= corr;
      mrun = mnew;
    }
    float psum = 0.0f;
#pragma unroll
    for (int kf = 0; kf < 4; ++kf) {
      bf16x4 pv;
#pragma unroll
      for (int j = 0; j < 4; ++j) {
        float e = exp2f(sc[kf][j] - mrun);
        psum += e;
        pv[j] = (__bf16)e;  // v_cvt_pk_bf16_f32 pairs
      }
      pb[kf] = __builtin_bit_cast(s16x4, pv);
    }
    psum += __shfl_xor(psum, 16);
    psum += __shfl_xor(psum, 32);
    lrun += psum;
  };

  for (int kt = 0; kt <= qt[1]; ++kt) {
    const int kb = kt * 64;
    if (kt) __syncthreads();  // prev tile's LDS reads done before overwrite
    // stage K: LDS linear, global d-chunk XOR-swizzled by key&7
#pragma unroll
    for (int r = 0; r < 2; ++r) {
      int c = r * 256 + tid;
      int key = c >> 3;
      int dcs = (c & 7) ^ (key & 7);
      GLOAD_LDS16(QKV + (size_t)(bb * Sz + kb + key) * 3072 + 1024 + hh * 64 + dcs * 8,
                  &Kt[c * 8]);
    }
    // stage V: LDS linear; source permuted so LDS holds subtiled layout
#pragma unroll
    for (int r = 0; r < 2; ++r) {
      int c = r * 256 + tid;
      int key = ((c >> 3) & 15) * 4 + ((c >> 1) & 3);
      int d = (c >> 7) * 16 + (c & 1) * 8;
      GLOAD_LDS16(QKV + (size_t)(bb * Sz + kb + key) * 3072 + 2048 + hh * 64 + d,
                  &Vs[c * 8]);
    }
    __syncthreads();

    s16x4 pb[2][4];
#pragma unroll
    for (int s = 0; s < 2; ++s)
      if (kt <= qt[s])
        proc(qf0[s], qf1[s], mr[s], lr[s], accO[s], pb[s], kt == qt[s], qg[s], kb);

    // O^T += V^T @ P^T — V-frags shared by both q-sets
#pragma unroll
    for (int df = 0; df < 4; ++df) {
      unsigned a = vbase + df * 2048;
      s16x4 vf0 = tr16<0>(a);
      s16x4 vf1 = tr16<512>(a);
      s16x4 vf2 = tr16<1024>(a);
      s16x4 vf3 = tr16<1536>(a);
      asm volatile("s_waitcnt lgkmcnt(0)" ::: "memory");
      __builtin_amdgcn_sched_barrier(0);
      __builtin_amdgcn_s_setprio(1);
#pragma unroll
      for (int s = 0; s < 2; ++s) {
        if (kt <= qt[s]) {
          accO[s][df] = mfma16(vf0, pb[s][0], accO[s][df]);
          accO[s][df] = mfma16(vf1, pb[s][1], accO[s][df]);
          accO[s][df] = mfma16(vf2, pb[s][2], accO[s][df]);
          accO[s][df] = mfma16(vf3, pb[s][3], accO[s][df]);
        }
      }
      __builtin_amdgcn_s_setprio(0);
    }
  }

#pragma unroll
  for (int s = 0; s < 2; ++s) {
    const float rl = 1.0f / lr[s];
    const size_t orow = (size_t)(bb * Sz + qg[s]) * Dz + hh * 64;
#pragma unroll
    for (int df = 0; df < 4; ++df) {
      s16x4 o;
#pragma unroll
      for (int j = 0; j < 4; ++j) o[j] = (short)f2bu(accO[s][df][j] * rl);
      *(s16x4*)&outA[orow + df * 16 + kgrp * 4] = o;
    }
  }
}

// ---------------- launch ----------------

extern "C" void kernel_launch(void* const* d_in, const int* in_sizes, int n_in,
                              void* d_out, int out_size, void* d_ws, size_t ws_size,
                              hipStream_t stream) {
  const float* x   = (const float*)d_in[0];
  // d_in[1] = mask (causal, known) — unused
  const float* wq  = (const float*)d_in[2];
  const float* wk  = (const float*)d_in[3];
  const float* wv  = (const float*)d_in[4];
  const float* wo  = (const float*)d_in[5];
  const float* w1  = (const float*)d_in[6];
  const float* b1  = (const float*)d_in[7];
  const float* w2  = (const float*)d_in[8];
  const float* b2  = (const float*)d_in[9];
  const float* g1  = (const float*)d_in[10];
  const float* be1 = (const float*)d_in[11];
  const float* g2  = (const float*)d_in[12];
  const float* be2 = (const float*)d_in[13];
  float* out = (float*)d_out;

  char* ws = (char*)d_ws;
  unsigned short* WqkvT = (unsigned short*)(ws);
  unsigned short* WoT   = (unsigned short*)(ws + 6291456);
  unsigned short* W1T   = (unsigned short*)(ws + 8388608);
  unsigned short* W2T   = (unsigned short*)(ws + 16777216);
  unsigned short* hbuf  = (unsigned short*)(ws + 25165824);
  unsigned short* big   = (unsigned short*)(ws + 41943040);  // QKV, later ff1

  dim3 tb(32, 8);
  pack_qkv<<<768, 256, 0, stream>>>(wq, wk, wv, WqkvT);
  transpose_f32_to_bf16<<<dim3(32, 32), tb, 0, stream>>>(wo, WoT, 1024, 1024);
  transpose_f32_to_bf16<<<dim3(128, 32), tb, 0, stream>>>(w1, W1T, 1024, 4096);
  transpose_f32_to_bf16<<<dim3(32, 128), tb, 0, stream>>>(w2, W2T, 4096, 1024);

  ln_kernel<<<Mz, 256, 0, stream>>>(x, g1, be1, hbuf);
  gemm128<EPI_BF16><<<1536, 256, 0, stream>>>(
      hbuf, WqkvT, Mz, 3072, 1024, nullptr, nullptr, big, nullptr);
  attn_kernel<<<dim3(16, 16, 4), 256, 0, stream>>>(big, hbuf);
  gemm128<EPI_RES_F32><<<512, 256, 0, stream>>>(
      hbuf, WoT, Mz, 1024, 1024, nullptr, x, nullptr, out);
  ln_kernel<<<Mz, 256, 0, stream>>>(out, g2, be2, hbuf);
  gemm128<EPI_GELU_BF16><<<2048, 256, 0, stream>>>(
      hbuf, W1T, Mz, Fz, 1024, b1, nullptr, big, nullptr);
  gemm128<EPI_BIAS_RES_F32><<<512, 256, 0, stream>>>(
      big, W2T, Mz, 1024, Fz, b2, out, nullptr, out);
}